// Round 11
// baseline (116.924 us; speedup 1.0000x reference)
//
#include <hip/hip_runtime.h>

// QueryAndGroup (PointNet++): ball query (R=0.2, nsample=32) + grouping.
// B=4, N=16384, NPOINT=2048, C=64, out = (B, 3+C, NPOINT, NSAMPLE) f32.
//
// R11 = R9/R10 resubmitted verbatim (both rounds hit GPU-broker
// acquisition timeouts; this source has never executed).
//
// Structure (2 kernels, NO transpose):
//   K1 bq_kernel: ONE WAVE per query. 1024-pt windows (16 consecutive
//     points/lane = 12 float4), process-then-prefetch, ballot-ordered
//     append, early exit at 32 hits (worst case 16 serial windows).
//     Writes idxbuf[8192][32] + the 3 grouped_xyz output channels.
//   K2 cg_kernel: CHANNEL-STATIONARY gather. Block = (b, c, query-half).
//     Stage feature column (b,c) (64 KB) -> LDS, then gather via idxbuf:
//     each pass = int4 idx load + 4 LDS reads + float4 nt store; each
//     wave stores 1 KB contiguous; each block writes a LINEAR 128 KB
//     region of out (fill-kernel write pattern ~6.3 TB/s). Pair-blocks
//     of one column sit 8 bids apart -> same XCD -> column HBM-read ~once.
//     Eliminates R2-R7's 16.8MB x2 transpose round-trip entirely.
//
// d2 uses __f*_rn in the reference's association ((dx^2+dy^2)+dz^2): no FMA
// contraction -> bit-identical ball mask vs numpy (R1-R7: absmax 0.0).

namespace {
constexpr int kN   = 16384;
constexpr int kNP  = 2048;
constexpr int kC   = 64;
constexpr int kNS  = 32;
constexpr int kOC  = 3 + kC;   // 67
constexpr int kWin = 1024;     // points per wave-window (16/lane)
}

typedef float vf4 __attribute__((ext_vector_type(4)));   // nt-store-able

__device__ __forceinline__ float d2_rn(float nx, float ny, float nz,
                                       float px, float py, float pz) {
    const float dx = __fsub_rn(nx, px);
    const float dy = __fsub_rn(ny, py);
    const float dz = __fsub_rn(nz, pz);
    return __fadd_rn(__fadd_rn(__fmul_rn(dx, dx), __fmul_rn(dy, dy)),
                     __fmul_rn(dz, dz));
}

// ---------- K1: ball query -> idxbuf + grouped_xyz channels ----------
__global__ __launch_bounds__(256) void bq_kernel(
    const float* __restrict__ xyz,      // (B, N, 3)
    const float* __restrict__ new_xyz,  // (B, NPOINT, 3)
    int*   __restrict__ idxbuf,         // (B*NPOINT, NSAMPLE)
    float* __restrict__ out)            // (B, 67, NPOINT, NSAMPLE)
{
    __shared__ int sIdx[4][kNS];
    const int t = threadIdx.x;
    const int w = t >> 6;
    const int l = t & 63;

    const int qid = (blockIdx.x << 2) | w;   // 0..8191
    const int b   = qid >> 11;
    const int j   = qid & 2047;

    const float* __restrict__ xb = xyz + (size_t)b * kN * 3;
    const float4* __restrict__ xv = reinterpret_cast<const float4*>(xb);
    const float* nxp = new_xyz + ((size_t)b * kNP + j) * 3;
    const float nx = nxp[0], ny = nxp[1], nz = nxp[2];
    const float R2 = 0.04f;

    // lane l covers points base+16l .. base+16l+15 (consecutive -> the
    // lane-prefix ordering below is index-order correct).
    int count = 0;
    float4 buf[12];
    {
        const int f0 = 12 * l;               // base=0: float4 index
        #pragma unroll
        for (int k = 0; k < 12; ++k) buf[k] = xv[f0 + k];
    }
    for (int base = 0; base < kN; base += kWin) {
        const float* p = reinterpret_cast<const float*>(buf);  // 48 floats
        unsigned int hm = 0;
        #pragma unroll
        for (int k = 0; k < 16; ++k) {
            const float d = d2_rn(nx, ny, nz, p[3*k], p[3*k+1], p[3*k+2]);
            hm |= (d < R2) ? (1u << k) : 0u;
        }
        // prefetch next window (buf consumed above)
        if (base + kWin < kN) {
            const int f0 = 3 * ((base + kWin) >> 2) + 12 * l;
            #pragma unroll
            for (int k = 0; k < 12; ++k) buf[k] = xv[f0 + k];
        }
        const unsigned long long m = (1ull << l) - 1ull;
        int pre = 0, wtot = 0;
        unsigned long long bal[16];
        #pragma unroll
        for (int k = 0; k < 16; ++k) {
            bal[k] = __ballot((hm >> k) & 1u);
            pre  += (int)__popcll(bal[k] & m);
            wtot += (int)__popcll(bal[k]);
        }
        int slot = count + pre;
        const int i0 = base + 16 * l;
        #pragma unroll
        for (int k = 0; k < 16; ++k) {
            if ((hm >> k) & 1u) { if (slot < kNS) sIdx[w][slot] = i0 + k; ++slot; }
        }
        count += wtot;
        if (count >= kNS) break;   // wave-uniform
    }
    __builtin_amdgcn_wave_barrier();

    // fill rule: count==0 -> all 0; else pad tail with first in-ball index
    if (count == 0) {
        if (l < kNS) sIdx[w][l] = 0;
    } else if (count < kNS) {
        const int first = sIdx[w][0];
        __builtin_amdgcn_wave_barrier();
        if (l >= count && l < kNS) sIdx[w][l] = first;
    }
    __builtin_amdgcn_wave_barrier();

    // idx out (coalesced 128B per wave)
    if (l < kNS) idxbuf[(size_t)qid * kNS + l] = sIdx[w][l];

    // grouped_xyz channels 0..2
    const int s = l & 31;
    const int h = l >> 5;
    if (h == 0) {
        const int id = sIdx[w][s];
        const size_t cs = (size_t)kNP * kNS;
        float* ob = out + ((size_t)b * kOC * kNP + j) * kNS + s;
        __builtin_nontemporal_store(xb[(size_t)id * 3 + 0] - nx, &ob[0 * cs]);
        __builtin_nontemporal_store(xb[(size_t)id * 3 + 1] - ny, &ob[1 * cs]);
        __builtin_nontemporal_store(xb[(size_t)id * 3 + 2] - nz, &ob[2 * cs]);
    }
}

// ---------- K2: channel-stationary gather (linear 128KB writes) ----------
__global__ __launch_bounds__(256) void cg_kernel(
    const float* __restrict__ feat,     // (B, C, N)
    const int*   __restrict__ idxbuf,   // (B*NPOINT, NSAMPLE)
    float* __restrict__ out)            // (B, 67, NPOINT, NSAMPLE)
{
    __shared__ float col[kN];            // 64 KB (static LDS limit)
    const int t = threadIdx.x;

    // bid and bid+8 -> same XCD (round-robin assumption, perf-only):
    // they handle the two query-halves of the SAME column -> one HBM fetch.
    const int bid = blockIdx.x;          // 0..511
    const int h   = (bid >> 3) & 1;
    const int u   = (bid & 7) | ((bid >> 4) << 3);   // 0..255 column id
    const int b   = u >> 6;
    const int c   = u & 63;

    // stage column -> LDS (coalesced float4)
    const float4* fv = reinterpret_cast<const float4*>(
        feat + ((size_t)b * kC + c) * kN);
    float4* cv = reinterpret_cast<float4*>(col);
    #pragma unroll
    for (int k = 0; k < 16; ++k) cv[t + k * 256] = fv[t + k * 256];
    __syncthreads();

    // gather: 1024 queries (this half), 32 samples each.
    // thread t -> (sq = t>>3 query-in-pass, s8 = int4 slot within query);
    // wave stores 8 queries x 32 samples x 4B = 1KB contiguous.
    const int sq = t >> 3;               // 0..31
    const int s8 = t & 7;                // int4 slot within query
    const int jbase = h << 10;
    float* ob = out + (((size_t)b * kOC + 3 + c) * kNP) * kNS;
    const int4* iv = reinterpret_cast<const int4*>(idxbuf);

    #pragma unroll 4
    for (int p = 0; p < 32; ++p) {
        const int j   = jbase + p * 32 + sq;         // 0..2047
        const int qid = (b << 11) | j;
        const int4 i4 = iv[(size_t)qid * 8 + s8];
        vf4 v;
        v.x = col[i4.x];
        v.y = col[i4.y];
        v.z = col[i4.z];
        v.w = col[i4.w];
        __builtin_nontemporal_store(
            v, reinterpret_cast<vf4*>(&ob[(size_t)j * kNS + (s8 << 2)]));
    }
}

// ---------- fallback (R1 kernel): direct gather from (C,N) ----------
__global__ __launch_bounds__(256) void qg_direct(
    const float* __restrict__ xyz, const float* __restrict__ new_xyz,
    const float* __restrict__ feat, float* __restrict__ out)
{
    __shared__ int sIdx[4][kNS];
    const int wave = threadIdx.x >> 6;
    const int lane = threadIdx.x & 63;
    const int bid  = blockIdx.x;
    const int xcd  = bid & 7;
    const int b    = xcd >> 1;
    const int jblk = ((xcd & 1) << 8) | (bid >> 3);
    const int j    = (jblk << 2) | wave;

    const float* __restrict__ xb = xyz + (size_t)b * kN * 3;
    const float* nxp = new_xyz + ((size_t)b * kNP + j) * 3;
    const float nx = nxp[0], ny = nxp[1], nz = nxp[2];
    const float R2 = 0.04f;

    int count = 0;
    for (int base = 0; base < kN; base += 64) {
        const int i = base + lane;
        const float d2 = d2_rn(nx, ny, nz, xb[(size_t)i * 3 + 0],
                               xb[(size_t)i * 3 + 1], xb[(size_t)i * 3 + 2]);
        const bool in = d2 < R2;
        const unsigned long long bal = __ballot(in);
        const int pre  = (int)__popcll(bal & ((1ull << lane) - 1ull));
        const int slot = count + pre;
        if (in && slot < kNS) sIdx[wave][slot] = i;
        count += (int)__popcll(bal);
        if (count >= kNS) break;
    }
    __builtin_amdgcn_wave_barrier();
    if (count == 0) {
        if (lane < kNS) sIdx[wave][lane] = 0;
    } else if (count < kNS) {
        const int first = sIdx[wave][0];
        __builtin_amdgcn_wave_barrier();
        if (lane >= count && lane < kNS) sIdx[wave][lane] = first;
    }
    __builtin_amdgcn_wave_barrier();

    const int s    = lane & 31;
    const int half = lane >> 5;
    const int id   = sIdx[wave][s];
    const float g0 = xb[(size_t)id * 3 + 0] - nx;
    const float g1 = xb[(size_t)id * 3 + 1] - ny;
    const float g2 = xb[(size_t)id * 3 + 2] - nz;
    const size_t cs = (size_t)kNP * kNS;
    float* ob = out + (((size_t)b * kOC) * kNP + j) * kNS + s;
    const float* fb = feat + ((size_t)b * kC) * kN + id;
    #pragma unroll
    for (int cb = 0; cb < kOC; cb += 2) {
        const int c = cb + half;
        if (c < kOC) {
            float v;
            if (c < 3) v = (c == 0) ? g0 : ((c == 1) ? g1 : g2);
            else       v = fb[(size_t)(c - 3) * kN];
            ob[(size_t)c * cs] = v;
        }
    }
}

extern "C" void kernel_launch(void* const* d_in, const int* in_sizes, int n_in,
                              void* d_out, int out_size, void* d_ws, size_t ws_size,
                              hipStream_t stream) {
    const float* xyz     = (const float*)d_in[0];
    const float* new_xyz = (const float*)d_in[1];
    const float* feat    = (const float*)d_in[2];
    float* out           = (float*)d_out;

    const size_t idx_bytes = (size_t)4 * kNP * kNS * sizeof(int);  // 1 MB
    if (ws_size >= idx_bytes) {
        int* idxbuf = (int*)d_ws;
        // K1: 8192 queries, 1 wave each.
        bq_kernel<<<dim3(2048), dim3(256), 0, stream>>>(
            xyz, new_xyz, idxbuf, out);
        // K2: 512 blocks = (b, c, query-half); linear 128KB writes each.
        cg_kernel<<<dim3(512), dim3(256), 0, stream>>>(feat, idxbuf, out);
    } else {
        qg_direct<<<dim3(2048), dim3(256), 0, stream>>>(xyz, new_xyz, feat, out);
    }
}

// Round 12
// 110.189 us; speedup vs baseline: 1.0611x; 1.0611x over previous
//
#include <hip/hip_runtime.h>

// QueryAndGroup (PointNet++): ball query (R=0.2, nsample=32) + grouping.
// B=4, N=16384, NPOINT=2048, C=64, out = (B, 3+C, NPOINT, NSAMPLE) f32.
//
// R12 = revert to R5, the best-measured variant (106.8 us). Six structural
// alternatives (R3/R4/R6/R7/R11) all landed 107-117; R5's fused per-wave
// bq->gather avoids any kernel boundary behind the ball-query straggler
// tail, which R4/R11 showed costs ~+10 us.
//
// Structure (2 kernels):
//   K1 tr_kernel: transpose features (B,C,N) -> tf (B,N,C) in ws
//     (nontemporal loads: feat read exactly once).
//   K2 qg_fused: ONE WAVE per query, fully wave-independent (no block
//     barriers). Phase 1: ball query, 4 pts/lane (3x float4, 1-deep
//     prefetch), 256-pt windows, ballot-only ordered append, early exit.
//     Phase 2: immediately gather this query (lane=(s,h): 8 float4 row
//     reads from tf) and write with nontemporal stores.
//
// d2 uses __f*_rn in the reference's association ((dx^2+dy^2)+dz^2): no FMA
// contraction -> bit-identical ball mask vs numpy (absmax 0.0 all rounds).

namespace {
constexpr int kN   = 16384;
constexpr int kNP  = 2048;
constexpr int kC   = 64;
constexpr int kNS  = 32;
constexpr int kOC  = 3 + kC;   // 67
constexpr int kWin = 256;      // points per wave-window (4/lane)
}

__device__ __forceinline__ float d2_rn(float nx, float ny, float nz,
                                       float px, float py, float pz) {
    const float dx = __fsub_rn(nx, px);
    const float dy = __fsub_rn(ny, py);
    const float dz = __fsub_rn(nz, pz);
    return __fadd_rn(__fadd_rn(__fmul_rn(dx, dx), __fmul_rn(dy, dy)),
                     __fmul_rn(dz, dz));
}

// ---------- K1: feature transpose (B,C,N) -> (B,N,C), nt loads ----------
__global__ __launch_bounds__(256) void tr_kernel(
    const float* __restrict__ feat, float* __restrict__ tf)
{
    __shared__ float tile[64][65];
    const int b  = blockIdx.x >> 8;
    const int n0 = (blockIdx.x & 255) << 6;
    const float* fb = feat + (size_t)b * kC * kN;
    float* ob       = tf   + (size_t)b * kN * kC;
    const int t  = threadIdx.x;
    const int q  = t >> 6;
    const int nn = t & 63;
    #pragma unroll
    for (int p = 0; p < 16; ++p) {
        const int c = p * 4 + q;
        tile[c][nn] = __builtin_nontemporal_load(&fb[(size_t)c * kN + n0 + nn]);
    }
    __syncthreads();
    const int cc = t & 63;
    #pragma unroll
    for (int p = 0; p < 16; ++p) {
        const int n = p * 4 + q;
        ob[(size_t)(n0 + n) * kC + cc] = tile[cc][n];
    }
}

// ---------- K2: fused per-wave ball query + gather, nt stores ----------
__global__ __launch_bounds__(256) void qg_fused(
    const float* __restrict__ xyz,      // (B, N, 3)
    const float* __restrict__ new_xyz,  // (B, NPOINT, 3)
    const float* __restrict__ tf,       // (B, N, C)
    float* __restrict__ out)            // (B, 67, NPOINT, NSAMPLE)
{
    __shared__ int sIdx[4][kNS];
    const int t = threadIdx.x;
    const int w = t >> 6;
    const int l = t & 63;

    // XCD-aware mapping: XCD pair {2b,2b+1} -> batch b (xyz/tf L2 locality).
    const int bid = blockIdx.x;          // 0..2047
    const int xcd = bid & 7;
    const int b   = xcd >> 1;
    const int jbl = ((xcd & 1) << 8) | (bid >> 3);   // 0..511
    const int j   = (jbl << 2) | w;      // 0..2047

    const float* __restrict__ xb = xyz + (size_t)b * kN * 3;
    const float4* __restrict__ xv = reinterpret_cast<const float4*>(xb);
    const float* nxp = new_xyz + ((size_t)b * kNP + j) * 3;
    const float nx = nxp[0], ny = nxp[1], nz = nxp[2];
    const float R2 = 0.04f;

    // ---- phase 1: ball query (wave-private, ballot-only, no barriers) ----
    int count = 0;
    float4 A0, A1, A2, B0, B1, B2;
    {
        const int o = 3 * l;                       // base=0 prefetch
        B0 = xv[o]; B1 = xv[o + 1]; B2 = xv[o + 2];
    }
    for (int base = 0; base < kN; base += kWin) {
        A0 = B0; A1 = B1; A2 = B2;
        if (base + kWin < kN) {
            const int o = ((base + kWin) >> 2) * 3 + 3 * l;
            B0 = xv[o]; B1 = xv[o + 1]; B2 = xv[o + 2];
        }
        const float d0  = d2_rn(nx, ny, nz, A0.x, A0.y, A0.z);
        const float d1  = d2_rn(nx, ny, nz, A0.w, A1.x, A1.y);
        const float d2v = d2_rn(nx, ny, nz, A1.z, A1.w, A2.x);
        const float d3  = d2_rn(nx, ny, nz, A2.y, A2.z, A2.w);
        const unsigned long long b0 = __ballot(d0  < R2);
        const unsigned long long b1 = __ballot(d1  < R2);
        const unsigned long long b2 = __ballot(d2v < R2);
        const unsigned long long b3 = __ballot(d3  < R2);

        const unsigned long long m = (1ull << l) - 1ull;
        int slot = count + (int)(__popcll(b0 & m) + __popcll(b1 & m) +
                                 __popcll(b2 & m) + __popcll(b3 & m));
        const int i0 = base + 4 * l;
        if (d0  < R2) { if (slot < kNS) sIdx[w][slot] = i0 + 0; ++slot; }
        if (d1  < R2) { if (slot < kNS) sIdx[w][slot] = i0 + 1; ++slot; }
        if (d2v < R2) { if (slot < kNS) sIdx[w][slot] = i0 + 2; ++slot; }
        if (d3  < R2) { if (slot < kNS) sIdx[w][slot] = i0 + 3; ++slot; }

        count += (int)(__popcll(b0) + __popcll(b1) +
                       __popcll(b2) + __popcll(b3));
        if (count >= kNS) break;   // wave-uniform
    }
    __builtin_amdgcn_wave_barrier();

    // fill rule: count==0 -> all 0; else pad tail with first in-ball index
    if (count == 0) {
        if (l < kNS) sIdx[w][l] = 0;
    } else if (count < kNS) {
        const int first = sIdx[w][0];
        __builtin_amdgcn_wave_barrier();
        if (l >= count && l < kNS) sIdx[w][l] = first;
    }
    __builtin_amdgcn_wave_barrier();

    // ---- phase 2: gather + nontemporal write ----
    const int s = l & 31;
    const int h = l >> 5;
    const int id = sIdx[w][s];

    const size_t cs = (size_t)kNP * kNS;
    float* ob = out + ((size_t)b * kOC * kNP + j) * kNS + s;

    if (h == 0) {
        const float g0 = xb[(size_t)id * 3 + 0] - nx;
        const float g1 = xb[(size_t)id * 3 + 1] - ny;
        const float g2 = xb[(size_t)id * 3 + 2] - nz;
        __builtin_nontemporal_store(g0, &ob[0 * cs]);
        __builtin_nontemporal_store(g1, &ob[1 * cs]);
        __builtin_nontemporal_store(g2, &ob[2 * cs]);
    }

    const float* row = tf + ((size_t)b * kN + id) * kC;
    float* obf = ob + 3 * cs;
    #pragma unroll
    for (int it = 0; it < 8; ++it) {
        const int chunk = it * 2 + h;    // 0..15
        const float4 v = *reinterpret_cast<const float4*>(row + chunk * 4);
        const size_t c0 = (size_t)chunk * 4;
        __builtin_nontemporal_store(v.x, &obf[(c0 + 0) * cs]);
        __builtin_nontemporal_store(v.y, &obf[(c0 + 1) * cs]);
        __builtin_nontemporal_store(v.z, &obf[(c0 + 2) * cs]);
        __builtin_nontemporal_store(v.w, &obf[(c0 + 3) * cs]);
    }
}

// ---------- fallback (R1 kernel): direct gather from (C,N) ----------
__global__ __launch_bounds__(256) void qg_direct(
    const float* __restrict__ xyz, const float* __restrict__ new_xyz,
    const float* __restrict__ feat, float* __restrict__ out)
{
    __shared__ int sIdx[4][kNS];
    const int wave = threadIdx.x >> 6;
    const int lane = threadIdx.x & 63;
    const int bid  = blockIdx.x;
    const int xcd  = bid & 7;
    const int b    = xcd >> 1;
    const int jblk = ((xcd & 1) << 8) | (bid >> 3);
    const int j    = (jblk << 2) | wave;

    const float* __restrict__ xb = xyz + (size_t)b * kN * 3;
    const float* nxp = new_xyz + ((size_t)b * kNP + j) * 3;
    const float nx = nxp[0], ny = nxp[1], nz = nxp[2];
    const float R2 = 0.04f;

    int count = 0;
    for (int base = 0; base < kN; base += 64) {
        const int i = base + lane;
        const float d2 = d2_rn(nx, ny, nz, xb[(size_t)i * 3 + 0],
                               xb[(size_t)i * 3 + 1], xb[(size_t)i * 3 + 2]);
        const bool in = d2 < R2;
        const unsigned long long bal = __ballot(in);
        const int pre  = (int)__popcll(bal & ((1ull << lane) - 1ull));
        const int slot = count + pre;
        if (in && slot < kNS) sIdx[wave][slot] = i;
        count += (int)__popcll(bal);
        if (count >= kNS) break;
    }
    __builtin_amdgcn_wave_barrier();
    if (count == 0) {
        if (lane < kNS) sIdx[wave][lane] = 0;
    } else if (count < kNS) {
        const int first = sIdx[wave][0];
        __builtin_amdgcn_wave_barrier();
        if (lane >= count && lane < kNS) sIdx[wave][lane] = first;
    }
    __builtin_amdgcn_wave_barrier();

    const int s    = lane & 31;
    const int half = lane >> 5;
    const int id   = sIdx[wave][s];
    const float g0 = xb[(size_t)id * 3 + 0] - nx;
    const float g1 = xb[(size_t)id * 3 + 1] - ny;
    const float g2 = xb[(size_t)id * 3 + 2] - nz;
    const size_t cs = (size_t)kNP * kNS;
    float* ob = out + (((size_t)b * kOC) * kNP + j) * kNS + s;
    const float* fb = feat + ((size_t)b * kC) * kN + id;
    #pragma unroll
    for (int cb = 0; cb < kOC; cb += 2) {
        const int c = cb + half;
        if (c < kOC) {
            float v;
            if (c < 3) v = (c == 0) ? g0 : ((c == 1) ? g1 : g2);
            else       v = fb[(size_t)(c - 3) * kN];
            ob[(size_t)c * cs] = v;
        }
    }
}

extern "C" void kernel_launch(void* const* d_in, const int* in_sizes, int n_in,
                              void* d_out, int out_size, void* d_ws, size_t ws_size,
                              hipStream_t stream) {
    const float* xyz     = (const float*)d_in[0];
    const float* new_xyz = (const float*)d_in[1];
    const float* feat    = (const float*)d_in[2];
    float* out           = (float*)d_out;

    const size_t tf_bytes = (size_t)4 * kN * kC * sizeof(float);   // 16.8 MB
    if (ws_size >= tf_bytes) {
        float* tf = (float*)d_ws;
        tr_kernel<<<dim3(1024), dim3(256), 0, stream>>>(feat, tf);
        qg_fused <<<dim3(2048), dim3(256), 0, stream>>>(xyz, new_xyz, tf, out);
    } else {
        qg_direct<<<dim3(2048), dim3(256), 0, stream>>>(xyz, new_xyz, feat, out);
    }
}